// Round 1
// baseline (750.462 us; speedup 1.0000x reference)
//
#include <hip/hip_runtime.h>
#include <hip/hip_bf16.h>
#include <math.h>

#define H 512
#define W 640
#define PHH 16
#define PWW 16
#define LPATCH 1280   // (512/16)*(640/16)
#define WBLK 40       // 640/16
#define NIMG 4
#define CDESC 128

// output offsets (floats)
#define OFF_K2D 0
#define OFF_COORDS 10240              // 4*1280*2
#define OFF_DESC  (10240 + 15360)     // + 4*3*1280
#define OFF_WGT   (10240 + 15360 + 655360) // + 4*128*1280

__device__ __forceinline__ float wave_max(float v) {
    #pragma unroll
    for (int off = 32; off > 0; off >>= 1) v = fmaxf(v, __shfl_xor(v, off, 64));
    return v;
}

// Kernel A: per-patch softmax attention + expected coords + weighted geometry
__global__ __launch_bounds__(256) void kp_attn(
    const float* __restrict__ geom,   // [N,3,H,W]
    const float* __restrict__ det,    // [N,1,H,W]
    float* __restrict__ out)
{
    const int blk = blockIdx.x;           // n*LPATCH + l
    const int n = blk / LPATCH;
    const int l = blk - n * LPATCH;
    const int hb = l / WBLK;
    const int wb = l - hb * WBLK;
    const int t  = threadIdx.x;           // patch pixel p = pi*16+pj
    const int pi = t >> 4;
    const int pj = t & 15;
    const int v = hb * PHH + pi;          // row
    const int u = wb * PWW + pj;          // col
    const size_t pix = (size_t)v * W + u;
    const size_t plane = (size_t)H * W;

    const float* gb = geom + (size_t)n * 3 * plane + pix;
    const float g0 = gb[0];
    const float g1 = gb[plane];
    const float g2 = gb[2 * plane];
    float s = det[(size_t)n * plane + pix];
    if (g0 * g0 + g1 * g1 + g2 * g2 == 0.0f) s = -20.0f;

    const int wid = t >> 6;
    __shared__ float sm[4];
    float m = wave_max(s);
    if ((t & 63) == 0) sm[wid] = m;
    __syncthreads();
    m = fmaxf(fmaxf(sm[0], sm[1]), fmaxf(sm[2], sm[3]));

    const float e = __expf(s - m);
    float a0 = e;
    float a1 = e * (float)u;
    float a2 = e * (float)v;
    float a3 = e * g0;
    float a4 = e * g1;
    float a5 = e * g2;
    #pragma unroll
    for (int off = 32; off > 0; off >>= 1) {
        a0 += __shfl_xor(a0, off, 64);
        a1 += __shfl_xor(a1, off, 64);
        a2 += __shfl_xor(a2, off, 64);
        a3 += __shfl_xor(a3, off, 64);
        a4 += __shfl_xor(a4, off, 64);
        a5 += __shfl_xor(a5, off, 64);
    }
    __shared__ float ss[6][4];
    if ((t & 63) == 0) {
        ss[0][wid] = a0; ss[1][wid] = a1; ss[2][wid] = a2;
        ss[3][wid] = a3; ss[4][wid] = a4; ss[5][wid] = a5;
    }
    __syncthreads();
    if (t == 0) {
        float S  = ss[0][0] + ss[0][1] + ss[0][2] + ss[0][3];
        float Su = ss[1][0] + ss[1][1] + ss[1][2] + ss[1][3];
        float Sv = ss[2][0] + ss[2][1] + ss[2][2] + ss[2][3];
        float S0 = ss[3][0] + ss[3][1] + ss[3][2] + ss[3][3];
        float S1 = ss[4][0] + ss[4][1] + ss[4][2] + ss[4][3];
        float S2 = ss[5][0] + ss[5][1] + ss[5][2] + ss[5][3];
        const float inv = 1.0f / S;
        const float eu = Su * inv;
        const float ev = Sv * inv;
        float* k2 = out + OFF_K2D + ((size_t)n * LPATCH + l) * 2;
        k2[0] = eu;
        k2[1] = ev;
        float* oc = out + OFF_COORDS + (size_t)n * 3 * LPATCH + l;
        oc[0]          = S0 * inv;
        oc[LPATCH]     = S1 * inv;
        oc[2 * LPATCH] = S2 * inv;
    }
}

__device__ __forceinline__ float tap(const float* __restrict__ p, float xf, float yf) {
    const bool valid = (xf >= 0.0f) && (xf <= (float)(W - 1)) &&
                       (yf >= 0.0f) && (yf <= (float)(H - 1));
    int xi = (int)xf; xi = xi < 0 ? 0 : (xi > W - 1 ? W - 1 : xi);
    int yi = (int)yf; yi = yi < 0 ? 0 : (yi > H - 1 ? H - 1 : yi);
    return valid ? p[(size_t)yi * W + xi] : 0.0f;
}

// Kernel B: bilinear sampling of descriptors (c<128) and weight_scores (c==128)
// grid: n * 129 * (LPATCH/256); threads over l -> coalesced writes
__global__ __launch_bounds__(256) void kp_sample(
    const float* __restrict__ desc,   // [N,128,H,W]
    const float* __restrict__ wsc,    // [N,1,H,W]
    float* __restrict__ out)
{
    int blk = blockIdx.x;
    const int lb = blk % 5;  blk /= 5;
    const int c  = blk % 129;
    const int n  = blk / 129;
    const int l  = lb * 256 + threadIdx.x;
    const size_t plane = (size_t)H * W;

    const float* k2 = out + OFF_K2D + ((size_t)n * LPATCH + l) * 2;
    const float eu = k2[0];
    const float ev = k2[1];
    const float un = 2.0f * eu / (float)(W - 1) - 1.0f;
    const float vn = 2.0f * ev / (float)(H - 1) - 1.0f;
    const float x = ((un + 1.0f) * (float)W - 1.0f) * 0.5f;
    const float y = ((vn + 1.0f) * (float)H - 1.0f) * 0.5f;
    const float x0 = floorf(x), y0 = floorf(y);
    const float x1 = x0 + 1.0f, y1 = y0 + 1.0f;
    const float wx1 = x - x0, wx0 = 1.0f - wx1;
    const float wy1 = y - y0, wy0 = 1.0f - wy1;

    const float* p;
    float* op;
    if (c < CDESC) {
        p  = desc + ((size_t)n * CDESC + c) * plane;
        op = out + OFF_DESC + ((size_t)n * CDESC + c) * LPATCH + l;
    } else {
        p  = wsc + (size_t)n * plane;
        op = out + OFF_WGT + (size_t)n * LPATCH + l;
    }
    const float r = tap(p, x0, y0) * (wx0 * wy0)
                  + tap(p, x1, y0) * (wx1 * wy0)
                  + tap(p, x0, y1) * (wx0 * wy1)
                  + tap(p, x1, y1) * (wx1 * wy1);
    *op = r;
}

extern "C" void kernel_launch(void* const* d_in, const int* in_sizes, int n_in,
                              void* d_out, int out_size, void* d_ws, size_t ws_size,
                              hipStream_t stream) {
    const float* geom = (const float*)d_in[0];   // geometry_img  [4,3,512,640]
    const float* desc = (const float*)d_in[1];   // descriptors   [4,128,512,640]
    const float* det  = (const float*)d_in[2];   // detector_scores [4,1,512,640]
    const float* wsc  = (const float*)d_in[3];   // weight_scores [4,1,512,640]
    float* out = (float*)d_out;

    kp_attn<<<NIMG * LPATCH, 256, 0, stream>>>(geom, det, out);
    kp_sample<<<NIMG * 129 * (LPATCH / 256), 256, 0, stream>>>(desc, wsc, out);
}

// Round 2
// 749.647 us; speedup vs baseline: 1.0011x; 1.0011x over previous
//
#include <hip/hip_runtime.h>
#include <hip/hip_bf16.h>
#include <math.h>

#define H 512
#define W 640
#define PHH 16
#define PWW 16
#define LPATCH 1280   // (512/16)*(640/16)
#define WBLK 40       // 640/16
#define NIMG 4
#define CDESC 128

// output offsets (floats)
#define OFF_K2D 0
#define OFF_COORDS 10240                    // 4*1280*2
#define OFF_DESC  (10240 + 15360)           // + 4*3*1280
#define OFF_WGT   (10240 + 15360 + 655360)  // + 4*128*1280

// Kernel A: per-patch softmax attention + expected coords + weighted geometry
__global__ __launch_bounds__(256) void kp_attn(
    const float* __restrict__ geom,   // [N,3,H,W]
    const float* __restrict__ det,    // [N,1,H,W]
    float* __restrict__ out)
{
    const int blk = blockIdx.x;           // n*LPATCH + l
    const int n = blk / LPATCH;
    const int l = blk - n * LPATCH;
    const int hb = l / WBLK;
    const int wb = l - hb * WBLK;
    const int t  = threadIdx.x;           // patch pixel p = pi*16+pj
    const int pi = t >> 4;
    const int pj = t & 15;
    const int v = hb * PHH + pi;          // row
    const int u = wb * PWW + pj;          // col
    const size_t pix = (size_t)v * W + u;
    const size_t plane = (size_t)H * W;

    const float* gb = geom + (size_t)n * 3 * plane + pix;
    const float g0 = gb[0];
    const float g1 = gb[plane];
    const float g2 = gb[2 * plane];
    float s = det[(size_t)n * plane + pix];
    if (g0 * g0 + g1 * g1 + g2 * g2 == 0.0f) s = -20.0f;

    const int wid = t >> 6;
    __shared__ float sm[4];
    float m = s;
    #pragma unroll
    for (int off = 32; off > 0; off >>= 1) m = fmaxf(m, __shfl_xor(m, off, 64));
    if ((t & 63) == 0) sm[wid] = m;
    __syncthreads();
    m = fmaxf(fmaxf(sm[0], sm[1]), fmaxf(sm[2], sm[3]));

    const float e = __expf(s - m);
    float a0 = e;
    float a1 = e * (float)u;
    float a2 = e * (float)v;
    float a3 = e * g0;
    float a4 = e * g1;
    float a5 = e * g2;
    #pragma unroll
    for (int off = 32; off > 0; off >>= 1) {
        a0 += __shfl_xor(a0, off, 64);
        a1 += __shfl_xor(a1, off, 64);
        a2 += __shfl_xor(a2, off, 64);
        a3 += __shfl_xor(a3, off, 64);
        a4 += __shfl_xor(a4, off, 64);
        a5 += __shfl_xor(a5, off, 64);
    }
    __shared__ float ss[6][4];
    if ((t & 63) == 0) {
        ss[0][wid] = a0; ss[1][wid] = a1; ss[2][wid] = a2;
        ss[3][wid] = a3; ss[4][wid] = a4; ss[5][wid] = a5;
    }
    __syncthreads();
    if (t == 0) {
        float S  = ss[0][0] + ss[0][1] + ss[0][2] + ss[0][3];
        float Su = ss[1][0] + ss[1][1] + ss[1][2] + ss[1][3];
        float Sv = ss[2][0] + ss[2][1] + ss[2][2] + ss[2][3];
        float S0 = ss[3][0] + ss[3][1] + ss[3][2] + ss[3][3];
        float S1 = ss[4][0] + ss[4][1] + ss[4][2] + ss[4][3];
        float S2 = ss[5][0] + ss[5][1] + ss[5][2] + ss[5][3];
        const float inv = 1.0f / S;
        float* k2 = out + OFF_K2D + ((size_t)n * LPATCH + l) * 2;
        k2[0] = Su * inv;
        k2[1] = Sv * inv;
        float* oc = out + OFF_COORDS + (size_t)n * 3 * LPATCH + l;
        oc[0]          = S0 * inv;
        oc[LPATCH]     = S1 * inv;
        oc[2 * LPATCH] = S2 * inv;
    }
}

// Kernel B v2: bilinear sampling. cg<64 -> channels cg and cg+64; cg==64 ->
// weight plane. 8 independent loads/thread for latency hiding; zero-pad
// validity folded into tap weights (all loads unconditional, clipped in-bounds).
__global__ __launch_bounds__(256) void kp_sample(
    const float* __restrict__ desc,   // [N,128,H,W]
    const float* __restrict__ wsc,    // [N,1,H,W]
    float* __restrict__ out)
{
    int blk = blockIdx.x;
    const int lb = blk % 5;  blk /= 5;
    const int cg = blk % 65;
    const int n  = blk / 65;
    const int l  = lb * 256 + threadIdx.x;
    const size_t plane = (size_t)H * W;

    const float* k2 = out + OFF_K2D + ((size_t)n * LPATCH + l) * 2;
    const float eu = k2[0];
    const float ev = k2[1];
    const float un = 2.0f * eu / (float)(W - 1) - 1.0f;
    const float vn = 2.0f * ev / (float)(H - 1) - 1.0f;
    const float x = ((un + 1.0f) * (float)W - 1.0f) * 0.5f;
    const float y = ((vn + 1.0f) * (float)H - 1.0f) * 0.5f;
    const float x0 = floorf(x), y0 = floorf(y);
    const float x1 = x0 + 1.0f, y1 = y0 + 1.0f;
    const float wx1 = x - x0, wx0 = 1.0f - wx1;
    const float wy1 = y - y0, wy0 = 1.0f - wy1;

    const bool vx0 = (x0 >= 0.0f) && (x0 <= (float)(W - 1));
    const bool vx1 = (x1 >= 0.0f) && (x1 <= (float)(W - 1));
    const bool vy0 = (y0 >= 0.0f) && (y0 <= (float)(H - 1));
    const bool vy1 = (y1 >= 0.0f) && (y1 <= (float)(H - 1));

    // validity folded into weights; indices clipped so loads stay in-bounds
    const float w00 = (vx0 && vy0) ? wx0 * wy0 : 0.0f;
    const float w10 = (vx1 && vy0) ? wx1 * wy0 : 0.0f;
    const float w01 = (vx0 && vy1) ? wx0 * wy1 : 0.0f;
    const float w11 = (vx1 && vy1) ? wx1 * wy1 : 0.0f;

    int xi0 = (int)x0; xi0 = xi0 < 0 ? 0 : (xi0 > W - 1 ? W - 1 : xi0);
    int xi1 = (int)x1; xi1 = xi1 < 0 ? 0 : (xi1 > W - 1 ? W - 1 : xi1);
    int yi0 = (int)y0; yi0 = yi0 < 0 ? 0 : (yi0 > H - 1 ? H - 1 : yi0);
    int yi1 = (int)y1; yi1 = yi1 < 0 ? 0 : (yi1 > H - 1 ? H - 1 : yi1);

    const size_t o00 = (size_t)yi0 * W + xi0;
    const size_t o10 = (size_t)yi0 * W + xi1;
    const size_t o01 = (size_t)yi1 * W + xi0;
    const size_t o11 = (size_t)yi1 * W + xi1;

    if (cg < 64) {
        const float* p1 = desc + ((size_t)n * CDESC + cg) * plane;
        const float* p2 = p1 + (size_t)64 * plane;
        // 8 independent loads in flight
        const float a00 = p1[o00], a10 = p1[o10], a01 = p1[o01], a11 = p1[o11];
        const float b00 = p2[o00], b10 = p2[o10], b01 = p2[o01], b11 = p2[o11];
        const float r1 = a00 * w00 + a10 * w10 + a01 * w01 + a11 * w11;
        const float r2 = b00 * w00 + b10 * w10 + b01 * w01 + b11 * w11;
        float* op = out + OFF_DESC + ((size_t)n * CDESC + cg) * LPATCH + l;
        op[0] = r1;
        op[(size_t)64 * LPATCH] = r2;
    } else {
        const float* p = wsc + (size_t)n * plane;
        const float r = p[o00] * w00 + p[o10] * w10 + p[o01] * w01 + p[o11] * w11;
        out[OFF_WGT + (size_t)n * LPATCH + l] = r;
    }
}

extern "C" void kernel_launch(void* const* d_in, const int* in_sizes, int n_in,
                              void* d_out, int out_size, void* d_ws, size_t ws_size,
                              hipStream_t stream) {
    const float* geom = (const float*)d_in[0];   // geometry_img  [4,3,512,640]
    const float* desc = (const float*)d_in[1];   // descriptors   [4,128,512,640]
    const float* det  = (const float*)d_in[2];   // detector_scores [4,1,512,640]
    const float* wsc  = (const float*)d_in[3];   // weight_scores [4,1,512,640]
    float* out = (float*)d_out;

    kp_attn<<<NIMG * LPATCH, 256, 0, stream>>>(geom, det, out);
    kp_sample<<<NIMG * 65 * (LPATCH / 256), 256, 0, stream>>>(desc, wsc, out);
}